// Round 1
// baseline (837.662 us; speedup 1.0000x reference)
//
#include <hip/hip_runtime.h>
#include <math.h>

// Fused vision-Mamba block, fp32 throughout (round 0: correctness-first).
// Pipeline: ln_split -> gemm<inproj> -> conv_silu -> gemm<xdbl> -> dt ->
//           scan p1/p2/p3 (chunked parallel scan, fused gating) ->
//           gemm<outproj> -> ln1 -> gemm<fc1+gelu> -> gemm<fc2+skip->xi layout> ->
//           gemm<W_out + batchnorm + silu>
// Workspace: 41,680,896 floats = 166.7 MB (regions reused across phases).

namespace {
constexpr int Lq    = 4096;
constexpr int Bq    = 4;
constexpr int Mrow  = 16 * Lq;   // 65536 mamba rows
constexpr float EPSV = 1e-5f;

__device__ __forceinline__ float sigmoidf_(float x) { return __fdividef(1.f, 1.f + __expf(-x)); }
__device__ __forceinline__ float siluf_(float x)    { return x * sigmoidf_(x); }
__device__ __forceinline__ float geluf_(float x)    { return 0.5f * x * (1.f + erff(x * 0.70710678118654752f)); }

// ---------------- K1: layernorm over C=256, write chunk-split xs (16,L,64) ----
__global__ __launch_bounds__(256) void k_ln_split(
    const float* __restrict__ x, const float* __restrict__ gw, const float* __restrict__ bw,
    float* __restrict__ xs)
{
    __shared__ float tile[256][33];
    __shared__ float smean[32], srstd[32];
    const int blk = blockIdx.x;           // b*128 + ltile
    const int b = blk >> 7, lt = blk & 127;
    const int l0 = lt << 5;
    const int tid = threadIdx.x;
    for (int e = tid; e < 256 * 32; e += 256) {
        int c = e >> 5, li = e & 31;
        tile[c][li] = x[(size_t)(b * 256 + c) * Lq + l0 + li];
    }
    __syncthreads();
    {
        int li = tid >> 3, part = tid & 7;
        float s = 0.f, s2 = 0.f;
        int c0 = part << 5;
        #pragma unroll 8
        for (int c = c0; c < c0 + 32; ++c) { float v = tile[c][li]; s += v; s2 += v * v; }
        s += __shfl_xor(s, 1); s2 += __shfl_xor(s2, 1);
        s += __shfl_xor(s, 2); s2 += __shfl_xor(s2, 2);
        s += __shfl_xor(s, 4); s2 += __shfl_xor(s2, 4);
        if (part == 0) {
            float mean = s * (1.f / 256.f);
            float var  = s2 * (1.f / 256.f) - mean * mean;
            smean[li] = mean; srstd[li] = rsqrtf(var + EPSV);
        }
    }
    __syncthreads();
    for (int e = tid; e < 256 * 32; e += 256) {
        int d = e & 63, r = e >> 6, li = r & 31, chunk = r >> 5;
        int c = (chunk << 6) + d;
        float v = (tile[c][li] - smean[li]) * srstd[li] * gw[c] + bw[c];
        xs[((size_t)((chunk * Bq + b) * Lq + l0 + li) << 6) + d] = v;
    }
}

// ---------------- generic tiled SGEMM: C = A(MxK) @ W(NxK)^T, epilogue by EPI --
// EPI 0: in_proj split store (out=xc_pre cols<128, out2=z)
// EPI 1: plain out[row*N+col]
// EPI 2: +bias(e0), gelu
// EPI 3: +bias(e0) + e1[0]*e2[row*64+col] (skip), store xi-interleaved layout
// EPI 4: batchnorm (e0=g,e1=b,e2=mean,e3=var) + silu, store (B,C,L) layout
template<int EPI>
__global__ __launch_bounds__(256) void k_gemm(
    const float* __restrict__ A, const float* __restrict__ W,
    float* __restrict__ out, float* __restrict__ out2,
    const float* __restrict__ e0, const float* __restrict__ e1,
    const float* __restrict__ e2, const float* __restrict__ e3,
    int M, int N, int K)
{
    __shared__ float As[64][65];   // [k][m], odd stride -> conflict-free
    __shared__ float Ws[64][65];   // [k][n]
    const int tid = threadIdx.x;
    const int tx = tid & 15, ty = tid >> 4;
    const int m0 = blockIdx.x << 6, n0 = blockIdx.y << 6;
    float acc[4][4] = {};
    for (int kb = 0; kb < K; kb += 64) {
        for (int e = tid; e < 4096; e += 256) {
            int k = e & 63, q = e >> 6;
            As[k][q] = A[(size_t)(m0 + q) * K + kb + k];
            int nc = n0 + q;
            Ws[k][q] = (nc < N) ? W[(size_t)nc * K + kb + k] : 0.f;
        }
        __syncthreads();
        #pragma unroll 8
        for (int k = 0; k < 64; ++k) {
            float av[4], wv[4];
            #pragma unroll
            for (int i = 0; i < 4; ++i) av[i] = As[k][(ty << 2) + i];
            #pragma unroll
            for (int j = 0; j < 4; ++j) wv[j] = Ws[k][(tx << 2) + j];
            #pragma unroll
            for (int i = 0; i < 4; ++i)
                #pragma unroll
                for (int j = 0; j < 4; ++j)
                    acc[i][j] += av[i] * wv[j];
        }
        __syncthreads();
    }
    #pragma unroll
    for (int i = 0; i < 4; ++i) {
        int row = m0 + (ty << 2) + i;
        #pragma unroll
        for (int j = 0; j < 4; ++j) {
            int col = n0 + (tx << 2) + j;
            if (col >= N) continue;
            float v = acc[i][j];
            if constexpr (EPI == 0) {
                if (col < 128) out [(size_t)row * 128 + col]         = v;
                else           out2[(size_t)row * 128 + (col - 128)] = v;
            } else if constexpr (EPI == 1) {
                out[(size_t)row * N + col] = v;
            } else if constexpr (EPI == 2) {
                out[(size_t)row * N + col] = geluf_(v + e0[col]);
            } else if constexpr (EPI == 3) {
                v += e0[col];
                v += e1[0] * e2[(size_t)row * 64 + col];
                int bb = row >> 12, l = row & (Lq - 1);
                int bbat = bb & 3, chunk = bb >> 2;
                out[((size_t)(bbat * Lq + l) << 8) + (col << 2) + chunk] = v;
            } else {  // EPI 4
                float scale = e0[col] * rsqrtf(e3[col] + EPSV);
                float bias  = e1[col] - e2[col] * scale;
                int bbat = row >> 12, l = row & (Lq - 1);
                out[((size_t)(bbat * 256 + col) << 12) + l] = siluf_(v * scale + bias);
            }
        }
    }
}

// ---------------- depthwise causal conv (KC=4) + bias + silu ------------------
__global__ __launch_bounds__(256) void k_conv(
    const float* __restrict__ xp, const float* __restrict__ wc,
    const float* __restrict__ bc, float* __restrict__ xc)
{
    const int g = blockIdx.x * 256 + threadIdx.x;   // Mrow*128 threads
    const int d = g & 127, row = g >> 7;
    const int l = row & (Lq - 1);
    float s = bc[d];
    #pragma unroll
    for (int k = 0; k < 4; ++k) {
        int l2 = l - 3 + k;
        if (l2 >= 0) s += xp[((size_t)(row - 3 + k) << 7) + d] * wc[d * 4 + k];
    }
    xc[((size_t)row << 7) + d] = siluf_(s);
}

// ---------------- dt = softplus(xdbl[:, :4] @ W_dt^T + b_dt) ------------------
__global__ __launch_bounds__(256) void k_dt(
    const float* __restrict__ xdbl, const float* __restrict__ wdt,
    const float* __restrict__ bdt, float* __restrict__ dt)
{
    const int g = blockIdx.x * 256 + threadIdx.x;   // Mrow*128 threads
    const int d = g & 127, row = g >> 7;
    const float* xr = xdbl + (size_t)row * 36;
    float s = bdt[d];
    #pragma unroll
    for (int r = 0; r < 4; ++r) s += xr[r] * wdt[d * 4 + r];
    float sp = (s > 20.f) ? s : log1pf(__expf(s));
    dt[((size_t)row << 7) + d] = sp;
}

// ---------------- scan pass1: per-chunk local scan (A-prod, h-local) ----------
// block: 256 thr = 16 d x 16 n; grid: bb(16) x chunk(16) x dgroup(8)
__global__ __launch_bounds__(256) void k_scan_p1(
    const float* __restrict__ dt, const float* __restrict__ xc,
    const float* __restrict__ xdbl, const float* __restrict__ alog,
    float* __restrict__ aprod, float* __restrict__ hloc)
{
    const int bx = blockIdx.x;
    const int dg = bx & 7, chunk = (bx >> 3) & 15, bb = bx >> 7;
    const int tid = threadIdx.x;
    const int n = tid & 15, dl = tid >> 4;
    const int d = (dg << 4) + dl;
    const float A_dn = -__expf(alog[d * 16 + n]);
    float h = 0.f, P = 1.f;
    const int t0 = bb * Lq + (chunk << 8);
    #pragma unroll 4
    for (int s = 0; s < 256; ++s) {
        const size_t t = (size_t)(t0 + s);
        float dtv = dt[(t << 7) + d];
        float xcv = xc[(t << 7) + d];
        float Bv  = xdbl[t * 36 + 4 + n];
        float av  = __expf(dtv * A_dn);
        h = av * h + dtv * Bv * xcv;
        P *= av;
    }
    const size_t idx = ((size_t)((bb * 128 + d) * 16 + n) << 4) + chunk;
    aprod[idx] = P; hloc[idx] = h;
}

// ---------------- scan pass2: exclusive scan across 16 chunks -----------------
__global__ __launch_bounds__(256) void k_scan_p2(
    const float* __restrict__ aprod, const float* __restrict__ hloc, float* __restrict__ hin)
{
    const int g = blockIdx.x * 256 + threadIdx.x;   // 32768 = bb*d*n
    const size_t base = (size_t)g << 4;
    float h = 0.f;
    #pragma unroll
    for (int c = 0; c < 16; ++c) {
        float a = aprod[base + c], hl = hloc[base + c];
        hin[base + c] = h;
        h = a * h + hl;
    }
}

// ---------------- scan pass3: re-run with h_in, y + gating fused --------------
__global__ __launch_bounds__(256) void k_scan_p3(
    const float* __restrict__ dt, const float* __restrict__ xc,
    const float* __restrict__ xdbl, const float* __restrict__ alog,
    const float* __restrict__ dpar, const float* __restrict__ z,
    const float* __restrict__ hin, float* __restrict__ yg)
{
    const int bx = blockIdx.x;
    const int dg = bx & 7, chunk = (bx >> 3) & 15, bb = bx >> 7;
    const int tid = threadIdx.x;
    const int n = tid & 15, dl = tid >> 4;
    const int d = (dg << 4) + dl;
    const float A_dn = -__expf(alog[d * 16 + n]);
    const float Dd = dpar[d];
    const size_t idx = ((size_t)((bb * 128 + d) * 16 + n) << 4) + chunk;
    float h = hin[idx];
    const int t0 = bb * Lq + (chunk << 8);
    #pragma unroll 2
    for (int s = 0; s < 256; ++s) {
        const size_t t = (size_t)(t0 + s);
        float dtv = dt[(t << 7) + d];
        float xcv = xc[(t << 7) + d];
        float Bv  = xdbl[t * 36 + 4 + n];
        float Cv  = xdbl[t * 36 + 20 + n];
        float av  = __expf(dtv * A_dn);
        h = av * h + dtv * Bv * xcv;
        float p = h * Cv;
        p += __shfl_xor(p, 1);
        p += __shfl_xor(p, 2);
        p += __shfl_xor(p, 4);
        p += __shfl_xor(p, 8);
        if (n == 0) {
            float zv = z[(t << 7) + d];
            yg[(t << 7) + d] = (p + xcv * Dd) * siluf_(zv);
        }
    }
}

// ---------------- ln1 over DM=64 (one wave per row) ---------------------------
__global__ __launch_bounds__(256) void k_ln1(
    const float* __restrict__ ym, const float* __restrict__ g1, const float* __restrict__ b1,
    float* __restrict__ yn)
{
    const int lane = threadIdx.x & 63;
    const size_t row = (size_t)blockIdx.x * 4 + (threadIdx.x >> 6);
    float v = ym[(row << 6) + lane];
    float s = v;
    s += __shfl_xor(s, 1);  s += __shfl_xor(s, 2);  s += __shfl_xor(s, 4);
    s += __shfl_xor(s, 8);  s += __shfl_xor(s, 16); s += __shfl_xor(s, 32);
    float mean = s * (1.f / 64.f);
    float dv = v - mean;
    float q = dv * dv;
    q += __shfl_xor(q, 1);  q += __shfl_xor(q, 2);  q += __shfl_xor(q, 4);
    q += __shfl_xor(q, 8);  q += __shfl_xor(q, 16); q += __shfl_xor(q, 32);
    float rstd = rsqrtf(q * (1.f / 64.f) + EPSV);
    yn[(row << 6) + lane] = dv * rstd * g1[lane] + b1[lane];
}

} // namespace

extern "C" void kernel_launch(void* const* d_in, const int* in_sizes, int n_in,
                              void* d_out, int out_size, void* d_ws, size_t ws_size,
                              hipStream_t stream)
{
    (void)in_sizes; (void)n_in; (void)out_size; (void)ws_size;
    const float* x      = (const float*)d_in[0];
    const float* g_norm = (const float*)d_in[1];
    const float* b_norm = (const float*)d_in[2];
    const float* g_n1   = (const float*)d_in[3];
    const float* b_n1   = (const float*)d_in[4];
    const float* W_in   = (const float*)d_in[5];
    const float* W_conv = (const float*)d_in[6];
    const float* b_conv = (const float*)d_in[7];
    const float* W_xp   = (const float*)d_in[8];
    const float* W_dt   = (const float*)d_in[9];
    const float* b_dt   = (const float*)d_in[10];
    const float* A_log  = (const float*)d_in[11];
    const float* D_par  = (const float*)d_in[12];
    const float* W_outp = (const float*)d_in[13];
    const float* skip_s = (const float*)d_in[14];
    const float* W_fc1  = (const float*)d_in[15];
    const float* b_fc1  = (const float*)d_in[16];
    const float* W_fc2  = (const float*)d_in[17];
    const float* b_fc2  = (const float*)d_in[18];
    const float* W_out  = (const float*)d_in[19];
    const float* bn_g   = (const float*)d_in[20];
    const float* bn_b   = (const float*)d_in[21];
    const float* bn_m   = (const float*)d_in[22];
    const float* bn_v   = (const float*)d_in[23];
    float* ws  = (float*)d_ws;
    float* out = (float*)d_out;

    // workspace layout (floats); total 41,680,896 floats = 166.7 MB
    float* XS    = ws;                   // 4,194,304   xs, live to fc2
    float* RA    = ws + 4194304;         // 8,388,608   xc_pre -> yg -> yn
    float* RB    = ws + 12582912;        // 8,388,608   z -> ym | xi
    float* XDBL  = ws + 20971520;        // 2,359,296
    float* XC    = ws + 23330816;        // 8,388,608
    float* DT    = ws + 31719424;        // 8,388,608
    float* APROD = ws + 40108032;        //   524,288
    float* HLOC  = ws + 40632320;        //   524,288
    float* HIN   = ws + 41156608;        //   524,288
    float* XCPRE = RA;  float* YG = RA;  float* YN = RA;        // sequential reuse
    float* Z     = RB;  float* YM = RB;  float* XI = RB + 4194304;
    float* H1    = XC;  // fc1 output spans XC+DT regions (16,777,216 floats), both dead by then

    k_ln_split<<<dim3(512), dim3(256), 0, stream>>>(x, g_norm, b_norm, XS);
    k_gemm<0><<<dim3(1024, 4), dim3(256), 0, stream>>>(XS, W_in, XCPRE, Z,
            nullptr, nullptr, nullptr, nullptr, Mrow, 256, 64);
    k_conv<<<dim3(32768), dim3(256), 0, stream>>>(XCPRE, W_conv, b_conv, XC);
    k_gemm<1><<<dim3(1024, 1), dim3(256), 0, stream>>>(XC, W_xp, XDBL, nullptr,
            nullptr, nullptr, nullptr, nullptr, Mrow, 36, 128);
    k_dt<<<dim3(32768), dim3(256), 0, stream>>>(XDBL, W_dt, b_dt, DT);
    k_scan_p1<<<dim3(2048), dim3(256), 0, stream>>>(DT, XC, XDBL, A_log, APROD, HLOC);
    k_scan_p2<<<dim3(128), dim3(256), 0, stream>>>(APROD, HLOC, HIN);
    k_scan_p3<<<dim3(2048), dim3(256), 0, stream>>>(DT, XC, XDBL, A_log, D_par, Z, HIN, YG);
    k_gemm<1><<<dim3(1024, 1), dim3(256), 0, stream>>>(YG, W_outp, YM, nullptr,
            nullptr, nullptr, nullptr, nullptr, Mrow, 64, 128);
    k_ln1<<<dim3(16384), dim3(256), 0, stream>>>(YM, g_n1, b_n1, YN);
    k_gemm<2><<<dim3(1024, 4), dim3(256), 0, stream>>>(YN, W_fc1, H1, nullptr,
            b_fc1, nullptr, nullptr, nullptr, Mrow, 256, 64);
    k_gemm<3><<<dim3(1024, 1), dim3(256), 0, stream>>>(H1, W_fc2, XI, nullptr,
            b_fc2, skip_s, XS, nullptr, Mrow, 64, 256);
    k_gemm<4><<<dim3(256, 4), dim3(256), 0, stream>>>(XI, W_out, out, nullptr,
            bn_g, bn_b, bn_m, bn_v, 16384, 256, 256);
}

// Round 2
// 670.207 us; speedup vs baseline: 1.2499x; 1.2499x over previous
//
#include <hip/hip_runtime.h>
#include <math.h>

// Fused vision-Mamba block, fp32. Round 1: scan restructured to n-vector-in-
// registers form (h[16]/thread), dt fused into scan, chunk A-product computed
// analytically as exp(A*sum(dt)). Workspace 161.5 MB.

namespace {
constexpr int Lq    = 4096;
constexpr int Bq    = 4;
constexpr int Mrow  = 16 * Lq;   // 65536 mamba rows
constexpr int NCH   = 128;       // chunks per sequence
constexpr int CHL   = 32;        // chunk length (NCH*CHL == Lq)
constexpr float EPSV = 1e-5f;

__device__ __forceinline__ float sigmoidf_(float x) { return __fdividef(1.f, 1.f + __expf(-x)); }
__device__ __forceinline__ float siluf_(float x)    { return x * sigmoidf_(x); }
__device__ __forceinline__ float geluf_(float x)    { return 0.5f * x * (1.f + erff(x * 0.70710678118654752f)); }
__device__ __forceinline__ float softplusf_(float x){ return (x > 20.f) ? x : log1pf(__expf(x)); }

// ---------------- K1: layernorm over C=256, write chunk-split xs (16,L,64) ----
__global__ __launch_bounds__(256) void k_ln_split(
    const float* __restrict__ x, const float* __restrict__ gw, const float* __restrict__ bw,
    float* __restrict__ xs)
{
    __shared__ float tile[256][33];
    __shared__ float smean[32], srstd[32];
    const int blk = blockIdx.x;           // b*128 + ltile
    const int b = blk >> 7, lt = blk & 127;
    const int l0 = lt << 5;
    const int tid = threadIdx.x;
    for (int e = tid; e < 256 * 32; e += 256) {
        int c = e >> 5, li = e & 31;
        tile[c][li] = x[(size_t)(b * 256 + c) * Lq + l0 + li];
    }
    __syncthreads();
    {
        int li = tid >> 3, part = tid & 7;
        float s = 0.f, s2 = 0.f;
        int c0 = part << 5;
        #pragma unroll 8
        for (int c = c0; c < c0 + 32; ++c) { float v = tile[c][li]; s += v; s2 += v * v; }
        s += __shfl_xor(s, 1); s2 += __shfl_xor(s2, 1);
        s += __shfl_xor(s, 2); s2 += __shfl_xor(s2, 2);
        s += __shfl_xor(s, 4); s2 += __shfl_xor(s2, 4);
        if (part == 0) {
            float mean = s * (1.f / 256.f);
            float var  = s2 * (1.f / 256.f) - mean * mean;
            smean[li] = mean; srstd[li] = rsqrtf(var + EPSV);
        }
    }
    __syncthreads();
    for (int e = tid; e < 256 * 32; e += 256) {
        int d = e & 63, r = e >> 6, li = r & 31, chunk = r >> 5;
        int c = (chunk << 6) + d;
        float v = (tile[c][li] - smean[li]) * srstd[li] * gw[c] + bw[c];
        xs[((size_t)((chunk * Bq + b) * Lq + l0 + li) << 6) + d] = v;
    }
}

// ---------------- generic tiled SGEMM: C = A(MxK) @ W(NxK)^T, epilogue by EPI --
template<int EPI>
__global__ __launch_bounds__(256) void k_gemm(
    const float* __restrict__ A, const float* __restrict__ W,
    float* __restrict__ out, float* __restrict__ out2,
    const float* __restrict__ e0, const float* __restrict__ e1,
    const float* __restrict__ e2, const float* __restrict__ e3,
    int M, int N, int K)
{
    __shared__ float As[64][65];
    __shared__ float Ws[64][65];
    const int tid = threadIdx.x;
    const int tx = tid & 15, ty = tid >> 4;
    const int m0 = blockIdx.x << 6, n0 = blockIdx.y << 6;
    float acc[4][4] = {};
    for (int kb = 0; kb < K; kb += 64) {
        for (int e = tid; e < 4096; e += 256) {
            int k = e & 63, q = e >> 6;
            As[k][q] = A[(size_t)(m0 + q) * K + kb + k];
            int nc = n0 + q;
            Ws[k][q] = (nc < N) ? W[(size_t)nc * K + kb + k] : 0.f;
        }
        __syncthreads();
        #pragma unroll 8
        for (int k = 0; k < 64; ++k) {
            float av[4], wv[4];
            #pragma unroll
            for (int i = 0; i < 4; ++i) av[i] = As[k][(ty << 2) + i];
            #pragma unroll
            for (int j = 0; j < 4; ++j) wv[j] = Ws[k][(tx << 2) + j];
            #pragma unroll
            for (int i = 0; i < 4; ++i)
                #pragma unroll
                for (int j = 0; j < 4; ++j)
                    acc[i][j] += av[i] * wv[j];
        }
        __syncthreads();
    }
    #pragma unroll
    for (int i = 0; i < 4; ++i) {
        int row = m0 + (ty << 2) + i;
        #pragma unroll
        for (int j = 0; j < 4; ++j) {
            int col = n0 + (tx << 2) + j;
            if (col >= N) continue;
            float v = acc[i][j];
            if constexpr (EPI == 0) {
                if (col < 128) out [(size_t)row * 128 + col]         = v;
                else           out2[(size_t)row * 128 + (col - 128)] = v;
            } else if constexpr (EPI == 1) {
                out[(size_t)row * N + col] = v;
            } else if constexpr (EPI == 2) {
                out[(size_t)row * N + col] = geluf_(v + e0[col]);
            } else if constexpr (EPI == 3) {
                v += e0[col];
                v += e1[0] * e2[(size_t)row * 64 + col];
                int bb = row >> 12, l = row & (Lq - 1);
                int bbat = bb & 3, chunk = bb >> 2;
                out[((size_t)(bbat * Lq + l) << 8) + (col << 2) + chunk] = v;
            } else {  // EPI 4
                float scale = e0[col] * rsqrtf(e3[col] + EPSV);
                float bias  = e1[col] - e2[col] * scale;
                int bbat = row >> 12, l = row & (Lq - 1);
                out[((size_t)(bbat * 256 + col) << 12) + l] = siluf_(v * scale + bias);
            }
        }
    }
}

// ---------------- depthwise causal conv (KC=4) + bias + silu ------------------
__global__ __launch_bounds__(256) void k_conv(
    const float* __restrict__ xp, const float* __restrict__ wc,
    const float* __restrict__ bc, float* __restrict__ xc)
{
    const int g = blockIdx.x * 256 + threadIdx.x;   // Mrow*128 threads
    const int d = g & 127, row = g >> 7;
    const int l = row & (Lq - 1);
    float s = bc[d];
    #pragma unroll
    for (int k = 0; k < 4; ++k) {
        int l2 = l - 3 + k;
        if (l2 >= 0) s += xp[((size_t)(row - 3 + k) << 7) + d] * wc[d * 4 + k];
    }
    xc[((size_t)row << 7) + d] = siluf_(s);
}

// ---------------- scan pass1: per-(d,chunk) thread, h[16] in regs -------------
// block 256 thr = 128 d x 2 chunks; grid = 16 bb x 64 chunk-pairs = 1024
// outputs: hloc[bb][chunk][d][16], dtsum[bb][chunk][d]
__global__ __launch_bounds__(256) void k_scan_p1(
    const float* __restrict__ xc, const float* __restrict__ xdbl,
    const float* __restrict__ alog, const float* __restrict__ wdt,
    const float* __restrict__ bdt,
    float* __restrict__ hloc, float* __restrict__ dtsum)
{
    __shared__ float xr[64 * 36];   // 64 xdbl rows (2 chunks x 32 steps)
    const int bb = blockIdx.x >> 6, cp = blockIdx.x & 63;
    const int tid = threadIdx.x;
    const int d = tid & 127, ch = tid >> 7;
    const int row0 = bb * Lq + cp * 64;
    for (int f = tid; f < 64 * 36; f += 256) xr[f] = xdbl[(size_t)row0 * 36 + f];
    __syncthreads();

    float A[16];
    {
        float Al[16];
        const float4* ap = (const float4*)(alog + d * 16);
        ((float4*)Al)[0] = ap[0]; ((float4*)Al)[1] = ap[1];
        ((float4*)Al)[2] = ap[2]; ((float4*)Al)[3] = ap[3];
        #pragma unroll
        for (int n = 0; n < 16; ++n) A[n] = -__expf(Al[n]);
    }
    const float4 wv = ((const float4*)wdt)[d];
    const float bdv = bdt[d];

    const int chunk = cp * 2 + ch;
    const size_t tbase = (size_t)bb * Lq + (size_t)chunk * CHL;
    float h[16];
    #pragma unroll
    for (int n = 0; n < 16; ++n) h[n] = 0.f;
    float dts = 0.f;
    for (int s = 0; s < CHL; ++s) {
        const size_t t = tbase + s;
        const float xcv = xc[(t << 7) + d];
        const float* rp = xr + (ch * CHL + s) * 36;
        const float4 din = ((const float4*)rp)[0];
        float sv = bdv + din.x * wv.x + din.y * wv.y + din.z * wv.z + din.w * wv.w;
        const float dtv = softplusf_(sv);
        dts += dtv;
        const float dtxc = dtv * xcv;
        float Bv[16];
        ((float4*)Bv)[0] = ((const float4*)rp)[1];
        ((float4*)Bv)[1] = ((const float4*)rp)[2];
        ((float4*)Bv)[2] = ((const float4*)rp)[3];
        ((float4*)Bv)[3] = ((const float4*)rp)[4];
        #pragma unroll
        for (int n = 0; n < 16; ++n) {
            float a = __expf(dtv * A[n]);
            h[n] = a * h[n] + dtxc * Bv[n];
        }
    }
    float* hp = hloc + ((((size_t)bb * NCH + chunk) * 128 + d) << 4);
    #pragma unroll
    for (int n = 0; n < 16; ++n) hp[n] = h[n];
    dtsum[((size_t)bb * NCH + chunk) * 128 + d] = dts;
}

// ---------------- scan pass2: exclusive scan across NCH chunks ----------------
// 32768 threads = (bb,d,n); P[c] = exp(dtsum[c]*A[d,n])
__global__ __launch_bounds__(256) void k_scan_p2(
    const float* __restrict__ hloc, const float* __restrict__ dtsum,
    const float* __restrict__ alog, float* __restrict__ hin)
{
    const int g = blockIdx.x * 256 + threadIdx.x;
    const int n = g & 15, d = (g >> 4) & 127, bb = g >> 11;
    const float A_dn = -__expf(alog[d * 16 + n]);
    float h = 0.f;
    for (int c = 0; c < NCH; ++c) {
        const size_t idx = ((((size_t)bb * NCH + c) * 128 + d) << 4) + n;
        hin[idx] = h;
        h = __expf(dtsum[((size_t)bb * NCH + c) * 128 + d] * A_dn) * h + hloc[idx];
    }
}

// ---------------- scan pass3: re-scan from h_in, y + gating fused -------------
__global__ __launch_bounds__(256) void k_scan_p3(
    const float* __restrict__ xc, const float* __restrict__ xdbl,
    const float* __restrict__ alog, const float* __restrict__ wdt,
    const float* __restrict__ bdt, const float* __restrict__ dpar,
    const float* __restrict__ z, const float* __restrict__ hin,
    float* __restrict__ yg)
{
    __shared__ float xr[64 * 36];
    const int bb = blockIdx.x >> 6, cp = blockIdx.x & 63;
    const int tid = threadIdx.x;
    const int d = tid & 127, ch = tid >> 7;
    const int row0 = bb * Lq + cp * 64;
    for (int f = tid; f < 64 * 36; f += 256) xr[f] = xdbl[(size_t)row0 * 36 + f];
    __syncthreads();

    float A[16];
    {
        float Al[16];
        const float4* ap = (const float4*)(alog + d * 16);
        ((float4*)Al)[0] = ap[0]; ((float4*)Al)[1] = ap[1];
        ((float4*)Al)[2] = ap[2]; ((float4*)Al)[3] = ap[3];
        #pragma unroll
        for (int n = 0; n < 16; ++n) A[n] = -__expf(Al[n]);
    }
    const float4 wv = ((const float4*)wdt)[d];
    const float bdv = bdt[d];
    const float Dd = dpar[d];

    const int chunk = cp * 2 + ch;
    const size_t tbase = (size_t)bb * Lq + (size_t)chunk * CHL;
    float h[16];
    {
        const float* hp = hin + ((((size_t)bb * NCH + chunk) * 128 + d) << 4);
        #pragma unroll
        for (int n = 0; n < 16; ++n) h[n] = hp[n];
    }
    for (int s = 0; s < CHL; ++s) {
        const size_t t = tbase + s;
        const float xcv = xc[(t << 7) + d];
        const float* rp = xr + (ch * CHL + s) * 36;
        const float4 din = ((const float4*)rp)[0];
        float sv = bdv + din.x * wv.x + din.y * wv.y + din.z * wv.z + din.w * wv.w;
        const float dtv = softplusf_(sv);
        const float dtxc = dtv * xcv;
        float Bv[16], Cv[16];
        ((float4*)Bv)[0] = ((const float4*)rp)[1];
        ((float4*)Bv)[1] = ((const float4*)rp)[2];
        ((float4*)Bv)[2] = ((const float4*)rp)[3];
        ((float4*)Bv)[3] = ((const float4*)rp)[4];
        ((float4*)Cv)[0] = ((const float4*)rp)[5];
        ((float4*)Cv)[1] = ((const float4*)rp)[6];
        ((float4*)Cv)[2] = ((const float4*)rp)[7];
        ((float4*)Cv)[3] = ((const float4*)rp)[8];
        float y = 0.f;
        #pragma unroll
        for (int n = 0; n < 16; ++n) {
            float a = __expf(dtv * A[n]);
            h[n] = a * h[n] + dtxc * Bv[n];
            y += h[n] * Cv[n];
        }
        const float zv = z[(t << 7) + d];
        yg[(t << 7) + d] = (y + xcv * Dd) * siluf_(zv);
    }
}

// ---------------- ln1 over DM=64 (one wave per row) ---------------------------
__global__ __launch_bounds__(256) void k_ln1(
    const float* __restrict__ ym, const float* __restrict__ g1, const float* __restrict__ b1,
    float* __restrict__ yn)
{
    const int lane = threadIdx.x & 63;
    const size_t row = (size_t)blockIdx.x * 4 + (threadIdx.x >> 6);
    float v = ym[(row << 6) + lane];
    float s = v;
    s += __shfl_xor(s, 1);  s += __shfl_xor(s, 2);  s += __shfl_xor(s, 4);
    s += __shfl_xor(s, 8);  s += __shfl_xor(s, 16); s += __shfl_xor(s, 32);
    float mean = s * (1.f / 64.f);
    float dv = v - mean;
    float q = dv * dv;
    q += __shfl_xor(q, 1);  q += __shfl_xor(q, 2);  q += __shfl_xor(q, 4);
    q += __shfl_xor(q, 8);  q += __shfl_xor(q, 16); q += __shfl_xor(q, 32);
    float rstd = rsqrtf(q * (1.f / 64.f) + EPSV);
    yn[(row << 6) + lane] = dv * rstd * g1[lane] + b1[lane];
}

} // namespace

extern "C" void kernel_launch(void* const* d_in, const int* in_sizes, int n_in,
                              void* d_out, int out_size, void* d_ws, size_t ws_size,
                              hipStream_t stream)
{
    (void)in_sizes; (void)n_in; (void)out_size; (void)ws_size;
    const float* x      = (const float*)d_in[0];
    const float* g_norm = (const float*)d_in[1];
    const float* b_norm = (const float*)d_in[2];
    const float* g_n1   = (const float*)d_in[3];
    const float* b_n1   = (const float*)d_in[4];
    const float* W_in   = (const float*)d_in[5];
    const float* W_conv = (const float*)d_in[6];
    const float* b_conv = (const float*)d_in[7];
    const float* W_xp   = (const float*)d_in[8];
    const float* W_dt   = (const float*)d_in[9];
    const float* b_dt   = (const float*)d_in[10];
    const float* A_log  = (const float*)d_in[11];
    const float* D_par  = (const float*)d_in[12];
    const float* W_outp = (const float*)d_in[13];
    const float* skip_s = (const float*)d_in[14];
    const float* W_fc1  = (const float*)d_in[15];
    const float* b_fc1  = (const float*)d_in[16];
    const float* W_fc2  = (const float*)d_in[17];
    const float* b_fc2  = (const float*)d_in[18];
    const float* W_out  = (const float*)d_in[19];
    const float* bn_g   = (const float*)d_in[20];
    const float* bn_b   = (const float*)d_in[21];
    const float* bn_m   = (const float*)d_in[22];
    const float* bn_v   = (const float*)d_in[23];
    float* ws  = (float*)d_ws;
    float* out = (float*)d_out;

    // workspace layout (floats); total 40,370,176 floats = 161.5 MB
    float* XS    = ws;                   // 4,194,304   live to fc2
    float* RA    = ws + 4194304;         // 8,388,608   xc_pre -> yg -> yn
    float* RB    = ws + 12582912;        // 8,388,608   z -> ym | xi
    float* XDBL  = ws + 20971520;        // 2,359,296   dead after scan p3
    float* XC    = ws + 23330816;        // 8,388,608   dead after scan p3
    float* HLOC  = ws + 31719424;        // 4,194,304   dead after p2
    float* HIN   = ws + 35913728;        // 4,194,304   dead after p3
    float* DTSUM = ws + 40108032;        //   262,144   dead after p2
    float* XCPRE = RA;  float* YG = RA;  float* YN = RA;        // sequential reuse
    float* Z     = RB;  float* YM = RB;  float* XI = RB + 4194304;
    float* H1    = XDBL; // fc1 out: 16,777,216 floats overlaying XDBL..HIN (all dead)

    k_ln_split<<<dim3(512), dim3(256), 0, stream>>>(x, g_norm, b_norm, XS);
    k_gemm<0><<<dim3(1024, 4), dim3(256), 0, stream>>>(XS, W_in, XCPRE, Z,
            nullptr, nullptr, nullptr, nullptr, Mrow, 256, 64);
    k_conv<<<dim3(32768), dim3(256), 0, stream>>>(XCPRE, W_conv, b_conv, XC);
    k_gemm<1><<<dim3(1024, 1), dim3(256), 0, stream>>>(XC, W_xp, XDBL, nullptr,
            nullptr, nullptr, nullptr, nullptr, Mrow, 36, 128);
    k_scan_p1<<<dim3(1024), dim3(256), 0, stream>>>(XC, XDBL, A_log, W_dt, b_dt,
            HLOC, DTSUM);
    k_scan_p2<<<dim3(128), dim3(256), 0, stream>>>(HLOC, DTSUM, A_log, HIN);
    k_scan_p3<<<dim3(1024), dim3(256), 0, stream>>>(XC, XDBL, A_log, W_dt, b_dt,
            D_par, Z, HIN, YG);
    k_gemm<1><<<dim3(1024, 1), dim3(256), 0, stream>>>(YG, W_outp, YM, nullptr,
            nullptr, nullptr, nullptr, nullptr, Mrow, 64, 128);
    k_ln1<<<dim3(16384), dim3(256), 0, stream>>>(YM, g_n1, b_n1, YN);
    k_gemm<2><<<dim3(1024, 4), dim3(256), 0, stream>>>(YN, W_fc1, H1, nullptr,
            b_fc1, nullptr, nullptr, nullptr, Mrow, 256, 64);
    k_gemm<3><<<dim3(1024, 1), dim3(256), 0, stream>>>(H1, W_fc2, XI, nullptr,
            b_fc2, skip_s, XS, nullptr, Mrow, 64, 256);
    k_gemm<4><<<dim3(256, 4), dim3(256), 0, stream>>>(XI, W_out, out, nullptr,
            bn_g, bn_b, bn_m, bn_v, 16384, 256, 256);
}

// Round 3
// 378.448 us; speedup vs baseline: 2.2134x; 1.7709x over previous
//
#include <hip/hip_runtime.h>
#include <hip/hip_bf16.h>
#include <math.h>

// Round 3: GEMM chain -> bf16 MFMA (16x16x32, fp32 accum), bf16 activations,
// fused epilogues (silu(z), gelu, LN1-in-epilogue, skip, BN+silu+transpose).
// Scan stays fp32 internally (XDBL fp32), NCH=64. Workspace ~114 MB.

namespace {
constexpr int Lq   = 4096;
constexpr int Mrow = 16 * Lq;    // 65536 mamba rows
constexpr int NCH  = 64;         // chunks per sequence
constexpr int CHL  = 64;         // chunk length
constexpr float EPSV = 1e-5f;

typedef __bf16 v8bf __attribute__((ext_vector_type(8)));
typedef float  v4f  __attribute__((ext_vector_type(4)));

__device__ __forceinline__ float sigmoidf_(float x) { return __fdividef(1.f, 1.f + __expf(-x)); }
__device__ __forceinline__ float siluf_(float x)    { return x * sigmoidf_(x); }
__device__ __forceinline__ float geluf_(float x)    { return 0.5f * x * (1.f + erff(x * 0.70710678118654752f)); }
__device__ __forceinline__ float softplusf_(float x){ return (x > 20.f) ? x : log1pf(__expf(x)); }

__device__ __forceinline__ unsigned short f2bf(float f) {
    __hip_bfloat16 h = __float2bfloat16(f);
    return *reinterpret_cast<unsigned short*>(&h);
}
__device__ __forceinline__ float bf2f(unsigned short u) {
    union { unsigned u; float f; } x; x.u = ((unsigned)u) << 16; return x.f;
}

// ---------------- pack all GEMM weights to bf16 (concatenated) ----------------
__global__ __launch_bounds__(256) void k_pack(
    const float* __restrict__ w_in, const float* __restrict__ w_xp,
    const float* __restrict__ w_outp, const float* __restrict__ w_fc1,
    const float* __restrict__ w_fc2, const float* __restrict__ w_out,
    unsigned short* __restrict__ wb)
{
    const int i = blockIdx.x * 256 + threadIdx.x;   // 131072 total
    float v;
    if (i < 16384)      v = w_in[i];
    else if (i < 24576) { int i2 = i - 16384; int r = i2 >> 7, c = i2 & 127;
                          v = (r < 36) ? w_xp[r * 128 + c] : 0.f; }
    else if (i < 32768) v = w_outp[i - 24576];
    else if (i < 49152) v = w_fc1[i - 32768];
    else if (i < 65536) v = w_fc2[i - 49152];
    else                v = w_out[i - 65536];
    wb[i] = f2bf(v);
}

// ---------------- K1: layernorm over C=256, write chunk-split xs bf16 ---------
__global__ __launch_bounds__(256) void k_ln_split(
    const float* __restrict__ x, const float* __restrict__ gw, const float* __restrict__ bw,
    unsigned short* __restrict__ xs)
{
    __shared__ float tile[256][33];
    __shared__ float smean[32], srstd[32];
    const int blk = blockIdx.x;
    const int b = blk >> 7, lt = blk & 127;
    const int l0 = lt << 5;
    const int tid = threadIdx.x;
    for (int e = tid; e < 256 * 32; e += 256) {
        int c = e >> 5, li = e & 31;
        tile[c][li] = x[(size_t)(b * 256 + c) * Lq + l0 + li];
    }
    __syncthreads();
    {
        int li = tid >> 3, part = tid & 7;
        float s = 0.f, s2 = 0.f;
        int c0 = part << 5;
        #pragma unroll 8
        for (int c = c0; c < c0 + 32; ++c) { float v = tile[c][li]; s += v; s2 += v * v; }
        s += __shfl_xor(s, 1); s2 += __shfl_xor(s2, 1);
        s += __shfl_xor(s, 2); s2 += __shfl_xor(s2, 2);
        s += __shfl_xor(s, 4); s2 += __shfl_xor(s2, 4);
        if (part == 0) {
            float mean = s * (1.f / 256.f);
            float var  = s2 * (1.f / 256.f) - mean * mean;
            smean[li] = mean; srstd[li] = rsqrtf(var + EPSV);
        }
    }
    __syncthreads();
    for (int e = tid; e < 256 * 32; e += 256) {
        int d = e & 63, r = e >> 6, li = r & 31, chunk = r >> 5;
        int c = (chunk << 6) + d;
        float v = (tile[c][li] - smean[li]) * srstd[li] * gw[c] + bw[c];
        xs[((size_t)((chunk * 4 + b) * Lq + l0 + li) << 6) + d] = f2bf(v);
    }
}

// ---------------- bf16 MFMA GEMM, tile 128x64, epilogue by EPI ----------------
// EPI 0: in_proj: n0<128 -> XCPRE bf16; else silu -> SZ bf16
// EPI 1: xdbl: direct fp32 store, stride 36, col<36
// EPI 2: out_proj + LN1 fused -> YN bf16 (N=64, e0=g1, e1=b1)
// EPI 3: fc1: gelu(v + e0[col]) -> H1 bf16
// EPI 4: fc2: v + e0[col] + e1[0]*xs -> XI bf16 interleaved layout
// EPI 5: W_out: BN(e0..e3) + silu -> outf fp32 transposed (B,C,L)
template<int EPI>
__global__ __launch_bounds__(256) void k_mgemm(
    const unsigned short* __restrict__ A, const unsigned short* __restrict__ W,
    int K, unsigned short* __restrict__ outb, unsigned short* __restrict__ outb2,
    float* __restrict__ outf, const float* __restrict__ e0, const float* __restrict__ e1,
    const float* __restrict__ e2, const float* __restrict__ e3,
    const unsigned short* __restrict__ eb)
{
    __shared__ unsigned short smA[128 * 72];   // A tile [128][64] pad 72 (also epilogue tile)
    __shared__ unsigned short smW[64 * 72];    // W tile [64][64] pad 72
    __shared__ float sAux[256];
    const int tid = threadIdx.x;
    const int w = tid >> 6, lane = tid & 63, lm = lane & 15, quad = lane >> 4;
    const int m0 = blockIdx.x << 7, n0 = blockIdx.y << 6;

    v4f acc[2][4];
    #pragma unroll
    for (int mi = 0; mi < 2; ++mi)
        #pragma unroll
        for (int ni = 0; ni < 4; ++ni) acc[mi][ni] = (v4f){0.f, 0.f, 0.f, 0.f};

    for (int kb = 0; kb < K; kb += 64) {
        for (int it = tid; it < 1024; it += 256) {
            int r = it >> 3, s = it & 7;
            uint4 v = *(const uint4*)(A + (size_t)(m0 + r) * K + kb + s * 8);
            *(uint4*)(smA + r * 72 + s * 8) = v;
        }
        for (int it = tid; it < 512; it += 256) {
            int r = it >> 3, s = it & 7;
            uint4 v = *(const uint4*)(W + (size_t)(n0 + r) * K + kb + s * 8);
            *(uint4*)(smW + r * 72 + s * 8) = v;
        }
        __syncthreads();
        #pragma unroll
        for (int ks = 0; ks < 2; ++ks) {
            const int koff = ks * 32 + quad * 8;
            v8bf a0 = *(const v8bf*)(smA + (w * 32 + lm) * 72 + koff);
            v8bf a1 = *(const v8bf*)(smA + (w * 32 + 16 + lm) * 72 + koff);
            v8bf bfr[4];
            #pragma unroll
            for (int ni = 0; ni < 4; ++ni)
                bfr[ni] = *(const v8bf*)(smW + (ni * 16 + lm) * 72 + koff);
            #pragma unroll
            for (int ni = 0; ni < 4; ++ni) {
                acc[0][ni] = __builtin_amdgcn_mfma_f32_16x16x32_bf16(a0, bfr[ni], acc[0][ni], 0, 0, 0);
                acc[1][ni] = __builtin_amdgcn_mfma_f32_16x16x32_bf16(a1, bfr[ni], acc[1][ni], 0, 0, 0);
            }
        }
        __syncthreads();
    }

    if constexpr (EPI == 1) {   // direct fp32 store, cols < 36
        #pragma unroll
        for (int mi = 0; mi < 2; ++mi)
            #pragma unroll
            for (int ni = 0; ni < 3; ++ni)
                #pragma unroll
                for (int r = 0; r < 4; ++r) {
                    int col = ni * 16 + lm;
                    if (col < 36) {
                        int row = m0 + w * 32 + mi * 16 + quad * 4 + r;
                        outf[(size_t)row * 36 + col] = acc[mi][ni][r];
                    }
                }
        return;
    }

    // stage bf16 tile in LDS (alias smA)
    unsigned short* et = smA;
    #pragma unroll
    for (int mi = 0; mi < 2; ++mi)
        #pragma unroll
        for (int ni = 0; ni < 4; ++ni)
            #pragma unroll
            for (int r = 0; r < 4; ++r) {
                int trow = w * 32 + mi * 16 + quad * 4 + r;
                et[trow * 72 + ni * 16 + lm] = f2bf(acc[mi][ni][r]);
            }
    __syncthreads();

    if constexpr (EPI == 0) {
        if (n0 < 128) {
            for (int e = tid; e < 8192; e += 256) {
                int r = e >> 6, c = e & 63;
                outb[(size_t)(m0 + r) * 128 + n0 + c] = et[r * 72 + c];
            }
        } else {
            for (int e = tid; e < 8192; e += 256) {
                int r = e >> 6, c = e & 63;
                float z = bf2f(et[r * 72 + c]);
                outb2[(size_t)(m0 + r) * 128 + (n0 - 128) + c] = f2bf(siluf_(z));
            }
        }
    } else if constexpr (EPI == 2) {
        if (tid < 128) {
            float s = 0.f, s2 = 0.f;
            #pragma unroll 8
            for (int c = 0; c < 64; ++c) { float v = bf2f(et[tid * 72 + c]); s += v; s2 += v * v; }
            float mean = s * (1.f / 64.f);
            float var  = s2 * (1.f / 64.f) - mean * mean;
            sAux[tid] = mean; sAux[128 + tid] = rsqrtf(var + EPSV);
        }
        __syncthreads();
        for (int e = tid; e < 8192; e += 256) {
            int r = e >> 6, c = e & 63;
            float v = (bf2f(et[r * 72 + c]) - sAux[r]) * sAux[128 + r] * e0[c] + e1[c];
            outb[(size_t)(m0 + r) * 64 + c] = f2bf(v);
        }
    } else if constexpr (EPI == 3) {
        for (int e = tid; e < 8192; e += 256) {
            int r = e >> 6, c = e & 63;
            float v = bf2f(et[r * 72 + c]) + e0[n0 + c];
            outb[(size_t)(m0 + r) * 256 + n0 + c] = f2bf(geluf_(v));
        }
    } else if constexpr (EPI == 4) {
        const float sk = e1[0];
        const int bb = m0 >> 12, bbat = bb & 3, chunk = bb >> 2;
        const int lbase = m0 & (Lq - 1);
        for (int e = tid; e < 8192; e += 256) {
            int r = e >> 6, c = e & 63;
            float v = bf2f(et[r * 72 + c]) + e0[c] + sk * bf2f(eb[(size_t)(m0 + r) * 64 + c]);
            outb[((size_t)(bbat * Lq + lbase + r) << 8) + (c << 2) + chunk] = f2bf(v);
        }
    } else {  // EPI 5
        if (tid < 64) {
            float sc = e0[n0 + tid] * rsqrtf(e3[n0 + tid] + EPSV);
            sAux[tid] = sc; sAux[64 + tid] = e1[n0 + tid] - e2[n0 + tid] * sc;
        }
        __syncthreads();
        const int b = m0 >> 12, l0 = m0 & (Lq - 1);
        for (int e = tid; e < 8192; e += 256) {
            int c = e >> 7, li = e & 127;
            float v = bf2f(et[li * 72 + c]) * sAux[c] + sAux[64 + c];
            outf[((size_t)(b * 256 + n0 + c) << 12) + l0 + li] = siluf_(v);
        }
    }
}

// ---------------- depthwise causal conv (KC=4) + bias + silu, bf16 io ---------
__global__ __launch_bounds__(256) void k_conv(
    const unsigned short* __restrict__ xp, const float* __restrict__ wc,
    const float* __restrict__ bc, unsigned short* __restrict__ xc)
{
    const int g = blockIdx.x * 256 + threadIdx.x;
    const int d = g & 127, row = g >> 7;
    const int l = row & (Lq - 1);
    float s = bc[d];
    #pragma unroll
    for (int k = 0; k < 4; ++k) {
        int l2 = l - 3 + k;
        if (l2 >= 0) s += bf2f(xp[((size_t)(row - 3 + k) << 7) + d]) * wc[d * 4 + k];
    }
    xc[((size_t)row << 7) + d] = f2bf(siluf_(s));
}

// ---------------- scan pass1: per-(d,chunk) thread, h[16] in regs -------------
// block 256 = 128 d x 2 chunks; grid = 16 bb x 32 chunk-pairs = 512
__global__ __launch_bounds__(256) void k_scan_p1(
    const unsigned short* __restrict__ xc, const float* __restrict__ xdbl,
    const float* __restrict__ alog, const float* __restrict__ wdt,
    const float* __restrict__ bdt,
    float* __restrict__ hloc, float* __restrict__ dtsum)
{
    __shared__ float xr[128 * 36];
    const int bb = blockIdx.x >> 5, cp = blockIdx.x & 31;
    const int tid = threadIdx.x;
    const int d = tid & 127, ch = tid >> 7;
    const int row0 = bb * Lq + cp * 128;
    for (int f = tid; f < 128 * 36; f += 256) xr[f] = xdbl[(size_t)row0 * 36 + f];
    __syncthreads();

    float A[16];
    {
        float Al[16];
        const float4* ap = (const float4*)(alog + d * 16);
        ((float4*)Al)[0] = ap[0]; ((float4*)Al)[1] = ap[1];
        ((float4*)Al)[2] = ap[2]; ((float4*)Al)[3] = ap[3];
        #pragma unroll
        for (int n = 0; n < 16; ++n) A[n] = -__expf(Al[n]);
    }
    const float4 wv = ((const float4*)wdt)[d];
    const float bdv = bdt[d];

    const int chunk = cp * 2 + ch;
    const size_t tbase = (size_t)bb * Lq + (size_t)chunk * CHL;
    float h[16];
    #pragma unroll
    for (int n = 0; n < 16; ++n) h[n] = 0.f;
    float dts = 0.f;
    for (int s = 0; s < CHL; ++s) {
        const size_t t = tbase + s;
        const float xcv = bf2f(xc[(t << 7) + d]);
        const float* rp = xr + (ch * CHL + s) * 36;
        const float4 din = ((const float4*)rp)[0];
        float sv = bdv + din.x * wv.x + din.y * wv.y + din.z * wv.z + din.w * wv.w;
        const float dtv = softplusf_(sv);
        dts += dtv;
        const float dtxc = dtv * xcv;
        float Bv[16];
        ((float4*)Bv)[0] = ((const float4*)rp)[1];
        ((float4*)Bv)[1] = ((const float4*)rp)[2];
        ((float4*)Bv)[2] = ((const float4*)rp)[3];
        ((float4*)Bv)[3] = ((const float4*)rp)[4];
        #pragma unroll
        for (int n = 0; n < 16; ++n) {
            float a = __expf(dtv * A[n]);
            h[n] = a * h[n] + dtxc * Bv[n];
        }
    }
    float* hp = hloc + ((((size_t)bb * NCH + chunk) * 128 + d) << 4);
    #pragma unroll
    for (int n = 0; n < 16; ++n) hp[n] = h[n];
    dtsum[((size_t)bb * NCH + chunk) * 128 + d] = dts;
}

// ---------------- scan pass2: exclusive scan across NCH chunks ----------------
__global__ __launch_bounds__(256) void k_scan_p2(
    const float* __restrict__ hloc, const float* __restrict__ dtsum,
    const float* __restrict__ alog, float* __restrict__ hin)
{
    const int g = blockIdx.x * 256 + threadIdx.x;   // 32768 = bb*d*n
    const int n = g & 15, d = (g >> 4) & 127, bb = g >> 11;
    const float A_dn = -__expf(alog[d * 16 + n]);
    float h = 0.f;
    #pragma unroll 4
    for (int c = 0; c < NCH; ++c) {
        const size_t idx = ((((size_t)bb * NCH + c) * 128 + d) << 4) + n;
        hin[idx] = h;
        h = __expf(dtsum[((size_t)bb * NCH + c) * 128 + d] * A_dn) * h + hloc[idx];
    }
}

// ---------------- scan pass3: re-scan from h_in, y + gating fused -------------
__global__ __launch_bounds__(256) void k_scan_p3(
    const unsigned short* __restrict__ xc, const float* __restrict__ xdbl,
    const float* __restrict__ alog, const float* __restrict__ wdt,
    const float* __restrict__ bdt, const float* __restrict__ dpar,
    const unsigned short* __restrict__ sz, const float* __restrict__ hin,
    unsigned short* __restrict__ yg)
{
    __shared__ float xr[128 * 36];
    const int bb = blockIdx.x >> 5, cp = blockIdx.x & 31;
    const int tid = threadIdx.x;
    const int d = tid & 127, ch = tid >> 7;
    const int row0 = bb * Lq + cp * 128;
    for (int f = tid; f < 128 * 36; f += 256) xr[f] = xdbl[(size_t)row0 * 36 + f];
    __syncthreads();

    float A[16];
    {
        float Al[16];
        const float4* ap = (const float4*)(alog + d * 16);
        ((float4*)Al)[0] = ap[0]; ((float4*)Al)[1] = ap[1];
        ((float4*)Al)[2] = ap[2]; ((float4*)Al)[3] = ap[3];
        #pragma unroll
        for (int n = 0; n < 16; ++n) A[n] = -__expf(Al[n]);
    }
    const float4 wv = ((const float4*)wdt)[d];
    const float bdv = bdt[d];
    const float Dd = dpar[d];

    const int chunk = cp * 2 + ch;
    const size_t tbase = (size_t)bb * Lq + (size_t)chunk * CHL;
    float h[16];
    {
        const float* hp = hin + ((((size_t)bb * NCH + chunk) * 128 + d) << 4);
        #pragma unroll
        for (int n = 0; n < 16; ++n) h[n] = hp[n];
    }
    for (int s = 0; s < CHL; ++s) {
        const size_t t = tbase + s;
        const float xcv = bf2f(xc[(t << 7) + d]);
        const float* rp = xr + (ch * CHL + s) * 36;
        const float4 din = ((const float4*)rp)[0];
        float sv = bdv + din.x * wv.x + din.y * wv.y + din.z * wv.z + din.w * wv.w;
        const float dtv = softplusf_(sv);
        const float dtxc = dtv * xcv;
        float Bv[16], Cv[16];
        ((float4*)Bv)[0] = ((const float4*)rp)[1];
        ((float4*)Bv)[1] = ((const float4*)rp)[2];
        ((float4*)Bv)[2] = ((const float4*)rp)[3];
        ((float4*)Bv)[3] = ((const float4*)rp)[4];
        ((float4*)Cv)[0] = ((const float4*)rp)[5];
        ((float4*)Cv)[1] = ((const float4*)rp)[6];
        ((float4*)Cv)[2] = ((const float4*)rp)[7];
        ((float4*)Cv)[3] = ((const float4*)rp)[8];
        float y = 0.f;
        #pragma unroll
        for (int n = 0; n < 16; ++n) {
            float a = __expf(dtv * A[n]);
            h[n] = a * h[n] + dtxc * Bv[n];
            y += h[n] * Cv[n];
        }
        const float szv = bf2f(sz[(t << 7) + d]);
        yg[(t << 7) + d] = f2bf((y + xcv * Dd) * szv);
    }
}

} // namespace

extern "C" void kernel_launch(void* const* d_in, const int* in_sizes, int n_in,
                              void* d_out, int out_size, void* d_ws, size_t ws_size,
                              hipStream_t stream)
{
    (void)in_sizes; (void)n_in; (void)out_size; (void)ws_size;
    const float* x      = (const float*)d_in[0];
    const float* g_norm = (const float*)d_in[1];
    const float* b_norm = (const float*)d_in[2];
    const float* g_n1   = (const float*)d_in[3];
    const float* b_n1   = (const float*)d_in[4];
    const float* W_in   = (const float*)d_in[5];
    const float* W_conv = (const float*)d_in[6];
    const float* b_conv = (const float*)d_in[7];
    const float* W_xp   = (const float*)d_in[8];
    const float* W_dt   = (const float*)d_in[9];
    const float* b_dt   = (const float*)d_in[10];
    const float* A_log  = (const float*)d_in[11];
    const float* D_par  = (const float*)d_in[12];
    const float* W_outp = (const float*)d_in[13];
    const float* skip_s = (const float*)d_in[14];
    const float* W_fc1  = (const float*)d_in[15];
    const float* b_fc1  = (const float*)d_in[16];
    const float* W_fc2  = (const float*)d_in[17];
    const float* b_fc2  = (const float*)d_in[18];
    const float* W_out  = (const float*)d_in[19];
    const float* bn_g   = (const float*)d_in[20];
    const float* bn_b   = (const float*)d_in[21];
    const float* bn_m   = (const float*)d_in[22];
    const float* bn_v   = (const float*)d_in[23];
    char* base = (char*)d_ws;
    float* out = (float*)d_out;

    // workspace layout (byte offsets), total ~113.8 MB
    unsigned short* XS    = (unsigned short*)(base);              //  8 MB
    unsigned short* XCPRE = (unsigned short*)(base +   8388608);  // 16 MB (alias YG)
    unsigned short* SZ    = (unsigned short*)(base +  25165824);  // 16 MB
    unsigned short* XC    = (unsigned short*)(base +  41943040);  // 16 MB (alias XI)
    float*          XDBL  = (float*)        (base +  58720256);   // 9.44 MB (alias YN)
    float*          HLOC  = (float*)        (base +  68157440);   //  8 MB
    float*          HIN   = (float*)        (base +  76546048);   //  8 MB
    float*          DTSUM = (float*)        (base +  84934656);   // 0.5 MB
    unsigned short* H1    = (unsigned short*)(base + 85458944);   // 32 MB
    unsigned short* WB    = (unsigned short*)(base + 119013376);  // 0.25 MB
    unsigned short* YG = XCPRE;
    unsigned short* XI = XC;
    unsigned short* YN = (unsigned short*)XDBL;
    unsigned short* WB_in   = WB;
    unsigned short* WB_xp   = WB + 16384;
    unsigned short* WB_outp = WB + 24576;
    unsigned short* WB_fc1  = WB + 32768;
    unsigned short* WB_fc2  = WB + 49152;
    unsigned short* WB_out  = WB + 65536;

    k_pack<<<dim3(512), dim3(256), 0, stream>>>(W_in, W_xp, W_outp, W_fc1, W_fc2, W_out, WB);
    k_ln_split<<<dim3(512), dim3(256), 0, stream>>>(x, g_norm, b_norm, XS);
    k_mgemm<0><<<dim3(512, 4), dim3(256), 0, stream>>>(XS, WB_in, 64, XCPRE, SZ,
            nullptr, nullptr, nullptr, nullptr, nullptr, nullptr);
    k_conv<<<dim3(32768), dim3(256), 0, stream>>>(XCPRE, W_conv, b_conv, XC);
    k_mgemm<1><<<dim3(512, 1), dim3(256), 0, stream>>>(XC, WB_xp, 128, nullptr, nullptr,
            XDBL, nullptr, nullptr, nullptr, nullptr, nullptr);
    k_scan_p1<<<dim3(512), dim3(256), 0, stream>>>(XC, XDBL, A_log, W_dt, b_dt, HLOC, DTSUM);
    k_scan_p2<<<dim3(128), dim3(256), 0, stream>>>(HLOC, DTSUM, A_log, HIN);
    k_scan_p3<<<dim3(512), dim3(256), 0, stream>>>(XC, XDBL, A_log, W_dt, b_dt,
            D_par, SZ, HIN, YG);
    k_mgemm<2><<<dim3(512, 1), dim3(256), 0, stream>>>(YG, WB_outp, 128, YN, nullptr,
            nullptr, g_n1, b_n1, nullptr, nullptr, nullptr);
    k_mgemm<3><<<dim3(512, 4), dim3(256), 0, stream>>>(YN, WB_fc1, 64, H1, nullptr,
            nullptr, b_fc1, nullptr, nullptr, nullptr, nullptr);
    k_mgemm<4><<<dim3(512, 1), dim3(256), 0, stream>>>(H1, WB_fc2, 256, XI, nullptr,
            nullptr, b_fc2, skip_s, nullptr, nullptr, XS);
    k_mgemm<5><<<dim3(128, 4), dim3(256), 0, stream>>>(XI, WB_out, 256, nullptr, nullptr,
            out, bn_g, bn_b, bn_m, bn_v, nullptr);
}